// Round 7
// baseline (571.769 us; speedup 1.0000x reference)
//
#include <hip/hip_runtime.h>
#include <stdint.h>

#define NN 8192
#define DD 64

using bf16x8 = __attribute__((ext_vector_type(8))) short;   // 8 bf16 (4 VGPRs)
using f32x4  = __attribute__((ext_vector_type(4))) float;   // MFMA C/D

__device__ __forceinline__ unsigned short f2bf(float f){
  // round-to-nearest-even fp32 -> bf16
  unsigned u = __float_as_uint(f);
  return (unsigned short)((u + 0x7FFFu + ((u >> 16) & 1u)) >> 16);
}

__device__ __forceinline__ unsigned long long shfl64_xor(unsigned long long v, int off){
  return (((unsigned long long)(unsigned)__shfl_xor((int)(v >> 32), off)) << 32)
       | (unsigned long long)(unsigned)__shfl_xor((int)(v & 0xFFFFFFFFu), off);
}

// =====================================================================
// K1: k_pre — transpose + squared norms + bf16 B-fragment build.
// chunk(b,g,m,q,c) = bf16 of x[b*64+g*16+c][m*32+q*8 .. +7],
// flat chunk index b*512 + g*128 + m*64 + q*16 + c.
// =====================================================================
__global__ __launch_bounds__(256) void k_pre(const float* __restrict__ x, float* __restrict__ xT,
                                             float* __restrict__ sq, int do_tr,
                                             uint4* __restrict__ xfrag, int do_frag){
  __shared__ float tile[64*65];
  const int tid = threadIdx.x;
  const int b = blockIdx.x;
  for (int k = 0; k < 4; ++k){
    const int idx4 = tid + k*256;
    const float4 v = ((const float4*)(x + (size_t)b*4096))[idx4];
    const int row = idx4 >> 4, d0 = (idx4 & 15) * 4;
    tile[row*65 + d0 + 0] = v.x;
    tile[row*65 + d0 + 1] = v.y;
    tile[row*65 + d0 + 2] = v.z;
    tile[row*65 + d0 + 3] = v.w;
  }
  __syncthreads();
  if (do_tr){
    const int jj = tid & 15;
    const int dq = tid >> 4;
    for (int k = 0; k < 4; ++k){
      const int d = dq + 16*k;
      float4 o;
      o.x = tile[(jj*4+0)*65 + d];
      o.y = tile[(jj*4+1)*65 + d];
      o.z = tile[(jj*4+2)*65 + d];
      o.w = tile[(jj*4+3)*65 + d];
      ((float4*)xT)[(size_t)d*2048 + b*16 + jj] = o;
    }
  }
  if (do_frag){
    for (int ch = tid; ch < 512; ch += 256){
      const int c  = ch & 15;
      const int q  = (ch >> 4) & 3;
      const int m  = (ch >> 6) & 1;
      const int gl = ch >> 7;
      const float* sp = tile + (gl*16 + c)*65 + m*32 + q*8;
      unsigned short h[8];
#pragma unroll
      for (int i2 = 0; i2 < 8; ++i2) h[i2] = f2bf(sp[i2]);
      uint4 o;
      o.x = (unsigned)h[0] | ((unsigned)h[1] << 16);
      o.y = (unsigned)h[2] | ((unsigned)h[3] << 16);
      o.z = (unsigned)h[4] | ((unsigned)h[5] << 16);
      o.w = (unsigned)h[6] | ((unsigned)h[7] << 16);
      xfrag[(size_t)b*512 + ch] = o;
    }
  }
  if (tid < 64){
    float acc = 0.f;
    const float* rp = tile + tid*65;
    for (int d = 0; d < 64; ++d) acc = fmaf(rp[d], rp[d], acc);
    sq[b*64 + tid] = acc;
  }
}

// =====================================================================
// exact 1024-col distance pass (bit-exact chain, dims ascending)
// =====================================================================
template<bool XT>
__device__ __forceinline__ void dists_1024(const float* __restrict__ x, const float* __restrict__ xT,
                                           const float* __restrict__ xi, int jbase, int tid,
                                           float acc[8][4]){
#pragma unroll
  for (int r = 0; r < 8; ++r)
#pragma unroll
    for (int q = 0; q < 4; ++q) acc[r][q] = 0.f;
  const int j0 = jbase + tid*4;
  for (int dq = 0; dq < 16; ++dq){
    float4 vj[4];
    if (XT){
#pragma unroll
      for (int s = 0; s < 4; ++s)
        vj[s] = ((const float4*)xT)[(size_t)(dq*4+s)*2048 + (j0 >> 2)];
    } else {
#pragma unroll
      for (int s = 0; s < 4; ++s){
        const int d = dq*4 + s;
        vj[s].x = x[(size_t)(j0+0)*64 + d];
        vj[s].y = x[(size_t)(j0+1)*64 + d];
        vj[s].z = x[(size_t)(j0+2)*64 + d];
        vj[s].w = x[(size_t)(j0+3)*64 + d];
      }
    }
#pragma unroll
    for (int r = 0; r < 8; ++r){
      const float4 wv = ((const float4*)(xi + r*64))[dq];
      acc[r][0] = fmaf(vj[0].x, wv.x, acc[r][0]);
      acc[r][1] = fmaf(vj[0].y, wv.x, acc[r][1]);
      acc[r][2] = fmaf(vj[0].z, wv.x, acc[r][2]);
      acc[r][3] = fmaf(vj[0].w, wv.x, acc[r][3]);
      acc[r][0] = fmaf(vj[1].x, wv.y, acc[r][0]);
      acc[r][1] = fmaf(vj[1].y, wv.y, acc[r][1]);
      acc[r][2] = fmaf(vj[1].z, wv.y, acc[r][2]);
      acc[r][3] = fmaf(vj[1].w, wv.y, acc[r][3]);
      acc[r][0] = fmaf(vj[2].x, wv.z, acc[r][0]);
      acc[r][1] = fmaf(vj[2].y, wv.z, acc[r][1]);
      acc[r][2] = fmaf(vj[2].z, wv.z, acc[r][2]);
      acc[r][3] = fmaf(vj[2].w, wv.z, acc[r][3]);
      acc[r][0] = fmaf(vj[3].x, wv.w, acc[r][0]);
      acc[r][1] = fmaf(vj[3].y, wv.w, acc[r][1]);
      acc[r][2] = fmaf(vj[3].z, wv.w, acc[r][2]);
      acc[r][3] = fmaf(vj[3].w, wv.w, acc[r][3]);
    }
  }
}

// =====================================================================
// K2a: k_samp — exact sampling pass + threshold -> tub[] (global).
// Bit-identical to the round-0 threshold derivation.
// =====================================================================
template<bool XT>
__global__ __launch_bounds__(256) void k_samp(const float* __restrict__ x, const float* __restrict__ xT,
                                              const float* __restrict__ sq, float* __restrict__ tub){
  __shared__ __align__(16) float xi[8*64];
  __shared__ float sqi_s[8];
  __shared__ __align__(16) float samp[8*1024];
  const int tid = threadIdx.x;
  const int i0 = blockIdx.x * 8;
  for (int t = tid; t < 8*64; t += 256) xi[t] = x[(size_t)i0*64 + t];
  if (tid < 8) sqi_s[tid] = sq[i0+tid];
  __syncthreads();
  float sqir[8];
#pragma unroll
  for (int r = 0; r < 8; ++r) sqir[r] = sqi_s[r];

  const int w0 = (blockIdx.x * 1024) & 8191;
  float acc[8][4];
  dists_1024<XT>(x, xT, xi, w0, tid, acc);
  float sqj[4];
#pragma unroll
  for (int q = 0; q < 4; ++q) sqj[q] = sq[w0 + tid*4 + q];
#pragma unroll
  for (int r = 0; r < 8; ++r)
#pragma unroll
    for (int q = 0; q < 4; ++q)
      samp[r*1024 + tid*4 + q] = (sqir[r] + sqj[q]) - 2.f*acc[r][q];
  __syncthreads();
  const int wv = tid >> 6, lane = tid & 63;
  for (int rr = 0; rr < 2; ++rr){
    const int r = wv + rr*4;
    float v[16];
#pragma unroll
    for (int k2 = 0; k2 < 16; ++k2) v[k2] = samp[r*1024 + lane + 64*k2];
    unsigned lo = 0u, hi = 0x7F800001u;
    while (hi - lo > 1u){
      const unsigned mid = (lo + hi) >> 1;
      const float pf = __uint_as_float(mid);
      int c = 0;
#pragma unroll
      for (int k2 = 0; k2 < 16; ++k2) c += (v[k2] < pf) ? 1 : 0;
#pragma unroll
      for (int off = 32; off; off >>= 1) c += __shfl_xor(c, off);
      if (c >= 32) hi = mid; else lo = mid;
    }
    if (lane == 0) tub[i0 + r] = __uint_as_float(hi);
  }
}

// =====================================================================
// K2b: k_filt — pure MFMA bf16 margin filter. No LDS, no barriers.
// Rigorous per-pair margin: bf16 products are EXACT in fp32 (7+7
// mantissa bits), so |dist_bf - dist| <= 2^-6*1.002*Sum|x_i,d||x_j,d|
// <= 0.0157*sqrt(sqi*sqj). We use 0.017*sqrt(sqi)*sqrt(sqj) + 0.002
// => provable superset.
// =====================================================================
__global__ __launch_bounds__(256) void k_filt(const float* __restrict__ x, const float* __restrict__ sq,
                                              const float* __restrict__ tub,
                                              const uint4* __restrict__ xfrag,
                                              unsigned char* __restrict__ nib){
  const int tid = threadIdx.x;
  const int l   = tid & 63;
  const int w   = tid >> 6;        // wave id 0..3
  const int qh  = l >> 4;          // K-group (input) / row-group (output)
  const int c16 = l & 15;          // A-row (input) / col (output)
  const int i0  = blockIdx.x * 8;

  // A fragments: all 64 lanes supply K-slots qh*8..+7 of row c16 (0 for c16>=8)
  bf16x8 a0, a1;
#pragma unroll
  for (int i2 = 0; i2 < 8; ++i2){ a0[i2] = 0; a1[i2] = 0; }
  if (c16 < 8){
    const float* ap = x + (size_t)(i0 + c16)*64 + qh*8;
#pragma unroll
    for (int i2 = 0; i2 < 8; ++i2){
      a0[i2] = (short)f2bf(ap[i2]);
      a1[i2] = (short)f2bf(ap[i2 + 32]);
    }
  }
  // output rows qh*4+rg (real only for l<32; pad lanes never consumed)
  float thr3[4], rs[4];
#pragma unroll
  for (int rg = 0; rg < 4; ++rg){
    int row = qh*4 + rg; row = (row < 8) ? row : 0;
    thr3[rg] = (tub[i0 + row] - sq[i0 + row]) + 0.002f;
    rs[rg]   = 0.017f * sqrtf(sq[i0 + row]);
  }

  const bf16x8* bfp = (const bf16x8*)xfrag + (size_t)w*128 + l;
  const float*  sqp = sq + w*16 + c16;
  unsigned char* nb = nib + (size_t)blockIdx.x*8192 + w*16 + c16;

  // 2-deep software pipeline, 2x unrolled, branch-free prefetch addresses
  bf16x8 A0 = bfp[0],   A1 = bfp[64];     float SA = sqp[0];
  bf16x8 B0 = bfp[512], B1 = bfp[512+64]; float SB = sqp[64];
  for (int it = 0; it < 128; it += 2){
    const int n2 = (it+2 < 128) ? it+2 : 126;
    const int n3 = (it+3 < 128) ? it+3 : 127;
    bf16x8 N0 = bfp[(size_t)n2*512], N1 = bfp[(size_t)n2*512 + 64];
    bf16x8 M0 = bfp[(size_t)n3*512], M1 = bfp[(size_t)n3*512 + 64];
    const float SN = sqp[n2*64], SM = sqp[n3*64];
    {
      f32x4 acc = {0.f, 0.f, 0.f, 0.f};
      acc = __builtin_amdgcn_mfma_f32_16x16x32_bf16(a0, A0, acc, 0, 0, 0);
      acc = __builtin_amdgcn_mfma_f32_16x16x32_bf16(a1, A1, acc, 0, 0, 0);
      const float sr = sqrtf(SA);
      unsigned m4 = 0u;
      m4 |= (fmaf(-rs[0], sr, fmaf(-2.f, acc[0], SA)) < thr3[0]) ? 1u : 0u;
      m4 |= (fmaf(-rs[1], sr, fmaf(-2.f, acc[1], SA)) < thr3[1]) ? 2u : 0u;
      m4 |= (fmaf(-rs[2], sr, fmaf(-2.f, acc[2], SA)) < thr3[2]) ? 4u : 0u;
      m4 |= (fmaf(-rs[3], sr, fmaf(-2.f, acc[3], SA)) < thr3[3]) ? 8u : 0u;
      const unsigned pm = (unsigned)__shfl((int)m4, (l + 16) & 63);
      if (l < 16) nb[it*64] = (unsigned char)(m4 | (pm << 4));
    }
    {
      f32x4 acc = {0.f, 0.f, 0.f, 0.f};
      acc = __builtin_amdgcn_mfma_f32_16x16x32_bf16(a0, B0, acc, 0, 0, 0);
      acc = __builtin_amdgcn_mfma_f32_16x16x32_bf16(a1, B1, acc, 0, 0, 0);
      const float sr = sqrtf(SB);
      unsigned m4 = 0u;
      m4 |= (fmaf(-rs[0], sr, fmaf(-2.f, acc[0], SB)) < thr3[0]) ? 1u : 0u;
      m4 |= (fmaf(-rs[1], sr, fmaf(-2.f, acc[1], SB)) < thr3[1]) ? 2u : 0u;
      m4 |= (fmaf(-rs[2], sr, fmaf(-2.f, acc[2], SB)) < thr3[2]) ? 4u : 0u;
      m4 |= (fmaf(-rs[3], sr, fmaf(-2.f, acc[3], SB)) < thr3[3]) ? 8u : 0u;
      const unsigned pm = (unsigned)__shfl((int)m4, (l + 16) & 63);
      if (l < 16) nb[(it+1)*64] = (unsigned char)(m4 | (pm << 4));
    }
    A0 = N0; A1 = N1; SA = SN;
    B0 = M0; B1 = M1; SB = SM;
  }
}

// =====================================================================
// K2c: k_csort — 2048 blocks x 4 rows, single-chain scan + exact fp32
// recompute, then wave-local top-64 selection (verified, absmax 0.0).
// __launch_bounds__(256,4): VGPR cap 128 — fits the ~100-VGPR body with
// NO scratch spill (round-6 regression: cap 64 -> 13MB spill traffic).
// =====================================================================
__global__ __launch_bounds__(256, 4) void k_csort(const float* __restrict__ x, const float* __restrict__ sq,
                                                  const float* __restrict__ tub,
                                                  const unsigned char* __restrict__ nib,
                                                  float* __restrict__ res, unsigned short* __restrict__ nn16){
  __shared__ __align__(16) float xi[4*68];     // padded stride 68
  __shared__ float sqi_s[4];
  __shared__ float tubs[4];
  __shared__ __align__(16) unsigned long long cand[4*512];
  __shared__ unsigned ccnt[4];
  const int tid  = threadIdx.x;
  const int grp  = blockIdx.x >> 1;            // nibble-map group 0..1023
  const int half = blockIdx.x & 1;             // 0: rows 0..3, 1: rows 4..7
  const int i0   = grp*8 + half*4;             // first global row of this block
  const unsigned rmask = half ? 0xF0F0F0F0u : 0x0F0F0F0Fu;

  for (int t = tid; t < 4*64; t += 256) xi[(t >> 6)*68 + (t & 63)] = x[(size_t)i0*64 + t];
  if (tid < 4){ sqi_s[tid] = sq[i0+tid]; tubs[tid] = tub[i0+tid]; ccnt[tid] = 0u; }
  for (int t = tid; t < 4*512; t += 256) cand[t] = ~0ULL;
  __syncthreads();

  // ---- Phase A: scan nibble half + exact recompute (single chain) ----
  const uint4* nb4 = (const uint4*)(nib + (size_t)grp*8192);
  for (int u = tid; u < 512; u += 256){
    const uint4 v4 = nb4[u];
    unsigned wds[4] = {v4.x & rmask, v4.y & rmask, v4.z & rmask, v4.w & rmask};
#pragma unroll
    for (int ww = 0; ww < 4; ++ww){
      unsigned wvv = wds[ww];
      while (wvv){
        const int bit = __builtin_ctz(wvv);
        wvv &= wvv - 1u;
        const int r = bit & 3;                 // works for both nibble halves
        const int j = u*16 + ww*4 + (bit >> 3);
        const float* xj = x + (size_t)j*64;
        const float* xr = xi + r*68;
        float acc = 0.f;
#pragma unroll
        for (int d4 = 0; d4 < 16; ++d4){
          const float4 vj4 = ((const float4*)xj)[d4];
          const float4 wi4 = ((const float4*)xr)[d4];
          acc = fmaf(vj4.x, wi4.x, acc);
          acc = fmaf(vj4.y, wi4.y, acc);
          acc = fmaf(vj4.z, wi4.z, acc);
          acc = fmaf(vj4.w, wi4.w, acc);
        }
        const float dist = (sqi_s[r] + sq[j]) - 2.f*acc;
        if (dist < tubs[r]){
          const unsigned pos = atomicAdd(&ccnt[r], 1u);
          if (pos < 512u){
            unsigned u2 = __float_as_uint(dist);
            u2 = ((int)u2 < 0) ? ~u2 : (u2 | 0x80000000u);
            cand[r*512 + pos] = (((unsigned long long)u2) << 13) | (unsigned)j;
          }
        }
      }
    }
  }
  __syncthreads();

  // ---- Phase B: per-wave exact top-64 selection + sort ----
  const int w = tid >> 6, lane = tid & 63;
  {
    const int r = w;                           // 4 waves, 1 row each
    unsigned long long k8[8];
#pragma unroll
    for (int t = 0; t < 8; ++t) k8[t] = cand[r*512 + lane + 64*t];

    const unsigned long long REALMAX = (1ULL << 45) - 1ULL;
    int creal = 0;
#pragma unroll
    for (int t = 0; t < 8; ++t) creal += (int)__popcll(__ballot(k8[t] <= REALMAX));

    unsigned long long K50;
    if (creal >= 50){
      unsigned long long lo = 0ULL, hi = REALMAX;
      while (lo < hi){
        const unsigned long long mid = lo + ((hi - lo) >> 1);
        int c = 0;
#pragma unroll
        for (int t = 0; t < 8; ++t) c += (int)__popcll(__ballot(k8[t] <= mid));
        if (c >= 50) hi = mid; else lo = mid + 1ULL;
      }
      K50 = hi;
    } else {
      K50 = ~0ULL;   // fewer than 50 reals: select all reals, pads fill the rest
    }

    // compact reals <= K50 into 64 padded slots (order arbitrary; sorted next)
    unsigned long long* buf = cand + r*512;
    buf[lane] = ~0ULL;
    int base = 0;
#pragma unroll
    for (int t = 0; t < 8; ++t){
      const bool pr = (k8[t] <= K50) && (k8[t] != ~0ULL);
      const unsigned long long bal = __ballot(pr);
      const int off = base + (int)__popcll(bal & ((1ULL << lane) - 1ULL));
      if (pr && off < 64) buf[off] = k8[t];
      base += (int)__popcll(bal);
    }
    unsigned long long key = buf[lane];

    // 64-wide bitonic sort across the wave (ascending)
#pragma unroll
    for (int k = 2; k <= 64; k <<= 1){
#pragma unroll
      for (int j = k >> 1; j > 0; j >>= 1){
        const unsigned long long p = shfl64_xor(key, j);
        const bool dirUp = ((lane & k) == 0);
        const bool lower = ((lane & j) == 0);
        const unsigned long long mn = (key < p) ? key : p;
        const unsigned long long mx = (key < p) ? p : key;
        key = (dirUp == lower) ? mn : mx;
      }
    }

    // epilogue — verbatim arithmetic from the original (bit-identical)
    float e = 0.f;
    if (lane < 50){
      unsigned u2 = (unsigned)(key >> 13);
      u2 = (u2 & 0x80000000u) ? (u2 & 0x7FFFFFFFu) : ~u2;
      e = expf(-__uint_as_float(u2) / 30.f);
    }
#pragma unroll
    for (int off = 32; off; off >>= 1) e += __shfl_down(e, off);
    if (lane == 0) res[i0+r] = e / 1500.f;
    if (lane < 16) nn16[(size_t)(i0+r)*16 + lane] = (unsigned short)(key & 8191ULL);
  }
}

// =====================================================================
// K2 (fallback): original exact k_cand (round-0 proven path).
// =====================================================================
template<bool XT>
__global__ __launch_bounds__(256) void k_cand(const float* __restrict__ x, const float* __restrict__ xT,
                                              const float* __restrict__ sq,
                                              float* __restrict__ res, unsigned short* __restrict__ nn16){
  __shared__ float xi[8*64];
  __shared__ float sqi_s[8];
  __shared__ float tubs[8];
  __shared__ __align__(16) unsigned long long cand[8*512];
  __shared__ unsigned ccnt[8];
  float* samp = (float*)cand;
  const int tid = threadIdx.x;
  const int i0 = blockIdx.x * 8;
  for (int t = tid; t < 8*64; t += 256) xi[t] = x[(size_t)i0*64 + t];
  if (tid < 8){ sqi_s[tid] = sq[i0+tid]; ccnt[tid] = 0u; }
  __syncthreads();
  float sqir[8];
#pragma unroll
  for (int r = 0; r < 8; ++r) sqir[r] = sqi_s[r];

  const int w0 = (blockIdx.x * 1024) & 8191;
  {
    float acc[8][4];
    dists_1024<XT>(x, xT, xi, w0, tid, acc);
    float sqj[4];
#pragma unroll
    for (int q = 0; q < 4; ++q) sqj[q] = sq[w0 + tid*4 + q];
#pragma unroll
    for (int r = 0; r < 8; ++r)
#pragma unroll
      for (int q = 0; q < 4; ++q)
        samp[r*1024 + tid*4 + q] = (sqir[r] + sqj[q]) - 2.f*acc[r][q];
  }
  __syncthreads();
  {
    const int wv = tid >> 6, lane = tid & 63;
    for (int rr = 0; rr < 2; ++rr){
      const int r = wv + rr*4;
      float v[16];
#pragma unroll
      for (int k2 = 0; k2 < 16; ++k2) v[k2] = samp[r*1024 + lane + 64*k2];
      unsigned lo = 0u, hi = 0x7F800001u;
      while (hi - lo > 1u){
        const unsigned mid = (lo + hi) >> 1;
        const float pf = __uint_as_float(mid);
        int c = 0;
#pragma unroll
        for (int k2 = 0; k2 < 16; ++k2) c += (v[k2] < pf) ? 1 : 0;
#pragma unroll
        for (int off = 32; off; off >>= 1) c += __shfl_xor(c, off);
        if (c >= 32) hi = mid; else lo = mid;
      }
      if (lane == 0) tubs[r] = __uint_as_float(hi);
    }
  }
  __syncthreads();
  float tubr[8];
#pragma unroll
  for (int r = 0; r < 8; ++r) tubr[r] = tubs[r];
  for (int t = tid; t < 8*512; t += 256) cand[t] = ~0ULL;
  __syncthreads();

  for (int pass = 0; pass < 8; ++pass){
    const int jb = pass*1024;
    float acc[8][4];
    dists_1024<XT>(x, xT, xi, jb, tid, acc);
    const int j0 = jb + tid*4;
    float sqj[4];
#pragma unroll
    for (int q = 0; q < 4; ++q) sqj[q] = sq[j0 + q];
#pragma unroll
    for (int r = 0; r < 8; ++r){
#pragma unroll
      for (int q = 0; q < 4; ++q){
        const float dist = (sqir[r] + sqj[q]) - 2.f*acc[r][q];
        if (dist < tubr[r]){
          const unsigned pos = atomicAdd(&ccnt[r], 1u);
          if (pos < 512u){
            unsigned u = __float_as_uint(dist);
            u = ((int)u < 0) ? ~u : (u | 0x80000000u);
            cand[r*512 + pos] = (((unsigned long long)u) << 13) | (unsigned)(j0 + q);
          }
        }
      }
    }
  }
  __syncthreads();

  for (int k = 2; k <= 512; k <<= 1){
    for (int jj2 = k >> 1; jj2 > 0; jj2 >>= 1){
      const int mm = tid;
      const int i = ((mm & ~(jj2-1)) << 1) | (mm & (jj2-1));
      const int p = i | jj2;
      const bool up2 = ((i & k) == 0);
#pragma unroll
      for (int r = 0; r < 8; ++r){
        unsigned long long a = cand[r*512+i], bb = cand[r*512+p];
        if ((a > bb) == up2){ cand[r*512+i] = bb; cand[r*512+p] = a; }
      }
      __syncthreads();
    }
  }

  const int wv2 = tid >> 6, lane2 = tid & 63;
  for (int rr = 0; rr < 2; ++rr){
    const int r = wv2*2 + rr;
    const unsigned long long kk = cand[r*512 + lane2];
    float e = 0.f;
    if (lane2 < 50){
      unsigned u2 = (unsigned)(kk >> 13);
      u2 = (u2 & 0x80000000u) ? (u2 & 0x7FFFFFFFu) : ~u2;
      e = expf(-__uint_as_float(u2) / 30.f);
    }
#pragma unroll
    for (int off = 32; off; off >>= 1) e += __shfl_down(e, off);
    if (lane2 == 0) res[i0+r] = e / 1500.f;
    if (lane2 < 16) nn16[(size_t)(i0+r)*16 + lane2] = (unsigned short)(kk & 8191ULL);
  }
}

// =====================================================================
// K3: k_rank — unchanged.
// =====================================================================
__global__ __launch_bounds__(256) void k_rank(const float* __restrict__ res,
                                              unsigned short* __restrict__ rank,
                                              float* __restrict__ dens_s){
  __shared__ __align__(16) unsigned long long keys[NN]; // 64KB
  __shared__ float red[256];
  __shared__ unsigned short pcnt[256];
  const int tid = threadIdx.x;
  float m = 0.f;
  for (int t = tid; t < NN; t += 256) m = fmaxf(m, res[t]);
  red[tid] = m; __syncthreads();
  for (int o = 128; o; o >>= 1){ if (tid < o) red[tid] = fmaxf(red[tid], red[tid+o]); __syncthreads(); }
  const float mr = red[0];
  __syncthreads();
  for (int t = tid; t < NN; t += 256){
    const float dnv = res[t] / mr;
    keys[t] = (((unsigned long long)__float_as_uint(dnv)) << 13) | (unsigned)t;
  }
  __syncthreads();
  const int i = blockIdx.x*128 + (tid & 127);
  const unsigned long long ki = keys[i];
  const int j0 = (tid >> 7) * (NN/2);      // wave-uniform half-split
  int c = 0;
#pragma unroll 8
  for (int j = 0; j < NN/2; ++j) c += (keys[j0 + j] < ki) ? 1 : 0;
  pcnt[tid] = (unsigned short)c;
  __syncthreads();
  if (tid < 128){
    const int r = (int)pcnt[tid] + (int)pcnt[tid + 128];
    rank[i] = (unsigned short)r;
    dens_s[r] = __uint_as_float((unsigned)(ki >> 13));   // bit-identical scatter
  }
}

// =====================================================================
// K4: k_ups — unchanged.
// =====================================================================
__global__ __launch_bounds__(256) void k_ups(const unsigned short* __restrict__ rank,
                                             const unsigned short* __restrict__ nn16,
                                             unsigned short* __restrict__ ups_t){
  __shared__ __align__(16) unsigned short rk[NN]; // 16KB
  const int tid = threadIdx.x;
  for (int t = tid; t < NN/8; t += 256) ((uint4*)rk)[t] = ((const uint4*)rank)[t];
  __syncthreads();
  const int o = blockIdx.x*256 + tid;
  const int p = rk[o];
  const uint4 n0 = ((const uint4*)nn16)[(size_t)o*2];
  const uint4 n1 = ((const uint4*)nn16)[(size_t)o*2 + 1];
  unsigned nw[8] = {n0.x, n0.y, n0.z, n0.w, n1.x, n1.y, n1.z, n1.w};
  unsigned short outv[16];
  int cnt = 0;
  for (int k = 0; k < 16; ++k){
    const unsigned nb = (nw[k >> 1] >> ((k & 1) * 16)) & 0xFFFFu;
    const unsigned r = rk[nb];
    if ((int)r > p){
      int q = cnt++;
      while (q > 0 && outv[q-1] < (unsigned short)r){ outv[q] = outv[q-1]; --q; }
      outv[q] = (unsigned short)r;
    }
  }
  for (int k = cnt; k < 16; ++k) outv[k] = 0;
  unsigned short* dst = ups_t + (size_t)p*16;
  uint4 a, b;
  a.x = (unsigned)outv[0] | ((unsigned)outv[1] << 16);
  a.y = (unsigned)outv[2] | ((unsigned)outv[3] << 16);
  a.z = (unsigned)outv[4] | ((unsigned)outv[5] << 16);
  a.w = (unsigned)outv[6] | ((unsigned)outv[7] << 16);
  b.x = (unsigned)outv[8] | ((unsigned)outv[9] << 16);
  b.y = (unsigned)outv[10] | ((unsigned)outv[11] << 16);
  b.z = (unsigned)outv[12] | ((unsigned)outv[13] << 16);
  b.w = (unsigned)outv[14] | ((unsigned)outv[15] << 16);
  ((uint4*)dst)[0] = a;
  ((uint4*)dst)[1] = b;
}

// =====================================================================
// K5: k_msf — Boruvka-MSF + replay (round-5 verified: wave-level scan,
// single-wave replay without inter-chunk flatten, single-wave top-10).
// =====================================================================
__device__ __forceinline__ unsigned uf_find2(volatile unsigned short* comp, unsigned x){
  unsigned r = comp[x];
  while (true){
    const unsigned g = comp[r];
    if (g == r) break;
    comp[x] = (unsigned short)g;
    x = r; r = g;
  }
  return r;
}

__global__ __launch_bounds__(1024) void k_msf(const float* __restrict__ dens_s,
                                              unsigned short* __restrict__ ups_t,
                                              unsigned long long* __restrict__ edges,
                                              int edgecap,
                                              float* __restrict__ out){
  __shared__ __align__(16) float dens[NN];              // 32KB
  __shared__ __align__(16) unsigned short P[NN];        // 16KB
  __shared__ __align__(16) unsigned short pkid[NN];     // 16KB
  __shared__ __align__(16) unsigned short death[NN];    // 16KB
  __shared__ __align__(16) unsigned short pkrank[4096]; // 8KB
  __shared__ __align__(16) unsigned short comp[4096];   // 8KB
  __shared__ __align__(16) unsigned short hook[4096];   // 8KB
  __shared__ __align__(16) unsigned bestv[4096];        // 16KB
  __shared__ __align__(16) unsigned long long msf[4096];// 32KB
  __shared__ unsigned long long sel[10];
  __shared__ unsigned ecnt_s, ecnt2_s, mcnt_s, chg_s, flat_s, dcnt_s;
  unsigned* scan1 = (unsigned*)msf;
  float* red = (float*)msf;
  unsigned* dlist = bestv;

  const int tid = threadIdx.x;
  const int lane = tid & 63;

  for (int t = tid; t < NN/4; t += 1024)
    ((float4*)dens)[t] = ((const float4*)dens_s)[t];
  for (int t = tid; t < NN; t += 1024){
    const unsigned u0 = ups_t[(size_t)t*16];
    P[t] = (u0 == 0u) ? (unsigned short)t : (unsigned short)u0;
    death[t] = 0xFFFFu;
  }
  if (tid == 0){ ecnt_s = 0u; mcnt_s = 0u; dcnt_s = 0u; }
  __syncthreads();

  for (int rd = 0; rd < 13; ++rd){
    for (int pp = 0; pp < 8; ++pp){
      const int p = tid + pp*1024;
      const unsigned v = P[p];
      const unsigned w2 = P[v];
      if (w2 != v) P[p] = (unsigned short)w2;
    }
    __syncthreads();
  }

  // --- peak-id scan: wave shfl scan + 16-wave-sum scan (2 barriers) ---
  {
    const int p0 = tid*8;
    int c = 0;
    for (int k = 0; k < 8; ++k) c += (P[p0+k] == (unsigned short)(p0+k)) ? 1 : 0;
    unsigned v = (unsigned)c;
    for (int s = 1; s < 64; s <<= 1){
      const unsigned o = (unsigned)__shfl_up((int)v, s);
      if (lane >= s) v += o;
    }
    if (lane == 63) scan1[1024 + (tid >> 6)] = v;      // wave totals
    __syncthreads();
    if (tid < 16){
      unsigned wv2 = scan1[1024 + tid];
      for (int s = 1; s < 16; s <<= 1){
        const unsigned o = (unsigned)__shfl_up((int)wv2, s);
        if (tid >= s) wv2 += o;
      }
      scan1[1040 + tid] = wv2;                         // inclusive wave prefix
    }
    __syncthreads();
    const unsigned woff = (tid >= 64) ? scan1[1040 + (tid >> 6) - 1] : 0u;
    const unsigned incl = v + woff;
    if (tid == 1023) scan1[1023] = incl;               // block total
    int base = (int)incl - c;
    for (int k = 0; k < 8; ++k){
      const int p = p0 + k;
      if (P[p] == (unsigned short)p){
        pkid[p] = (unsigned short)base;
        if (base < 4096) pkrank[base] = (unsigned short)p;
        ++base;
      }
    }
  }
  __syncthreads();
  int Npk = (int)scan1[1023];
  if (Npk > 4096) Npk = 4096;
  __syncthreads();

  for (int pp = 0; pp < 8; ++pp){
    const int p = tid + pp*1024;
    const uint4 a4 = ((const uint4*)ups_t)[(size_t)p*2];
    const uint4 b4 = ((const uint4*)ups_t)[(size_t)p*2 + 1];
    unsigned uu[8] = {a4.x, a4.y, a4.z, a4.w, b4.x, b4.y, b4.z, b4.w};
    unsigned edv[15];
    int nd = 0;
    const unsigned u0 = uu[0] & 0xFFFFu;
    if (u0 != 0u){
      const unsigned m0 = P[u0];
      const unsigned m0id = pkid[m0];
      for (int k = 1; k < 16; ++k){
        const unsigned uk = (uu[k >> 1] >> ((k & 1) * 16)) & 0xFFFFu;
        if (uk == 0u) break;
        const unsigned v = P[uk];
        if (v == m0) continue;
        const unsigned vid = pkid[v];
        bool dup = false;
        for (int j = 0; j < nd; ++j) dup = dup || ((edv[j] >> 16) == vid);
        if (dup) continue;
        edv[nd++] = (vid << 16) | m0id;
      }
    }
    unsigned off = (unsigned)nd;
    for (int s = 1; s < 64; s <<= 1){
      const unsigned o = (unsigned)__shfl_up((int)off, s);
      if (lane >= s) off += o;
    }
    const unsigned tot = (unsigned)__shfl((int)off, 63);
    unsigned wb = 0u;
    if (lane == 0 && tot) wb = atomicAdd(&ecnt_s, tot);
    wb = (unsigned)__shfl((int)wb, 0);
    const unsigned mybase = wb + off - (unsigned)nd;
    for (int k = 0; k < nd; ++k){
      const unsigned pos = mybase + (unsigned)k;
      if ((int)pos < edgecap)
        edges[pos] = (((unsigned long long)(unsigned)p) << 32) | (unsigned long long)edv[k];
    }
  }
  __syncthreads();
  int Ecur = ((int)ecnt_s < edgecap) ? (int)ecnt_s : edgecap;

  unsigned long long* eb_in  = edges;
  unsigned long long* eb_out = (unsigned long long*)ups_t;
  for (int t = tid; t < Npk; t += 1024) comp[t] = (unsigned short)t;
  __syncthreads();
  for (int round = 0; round < 16 && Ecur > 0; ++round){
    for (int t = tid; t < Npk; t += 1024){ bestv[t] = 0u; hook[t] = 0xFFFFu; }
    if (tid == 0){ chg_s = 0u; ecnt2_s = 0u; }
    __syncthreads();
    for (int base = 0; base < Ecur; base += 1024){
      const int e = base + tid;
      bool keep = false;
      unsigned long long ed = 0ULL;
      if (e < Ecur){
        ed = eb_in[e];
        const unsigned a = (unsigned)(ed >> 16) & 0xFFFFu;
        const unsigned b = (unsigned)ed & 0xFFFFu;
        const unsigned ra = comp[a], rb = comp[b];
        if (ra != rb){
          keep = true;
          const unsigned key = ((((unsigned)(ed >> 32)) + 1u) << 18) | (unsigned)e;
          atomicMax(&bestv[ra], key);
          atomicMax(&bestv[rb], key);
        }
      }
      const unsigned long long bal = __ballot(keep);
      const unsigned cnt = (unsigned)__popcll(bal);
      const unsigned pfx = (unsigned)__popcll(bal & ((1ULL << lane) - 1ULL));
      unsigned wb = 0u;
      if (lane == 0 && cnt) wb = atomicAdd(&ecnt2_s, cnt);
      wb = (unsigned)__shfl((int)wb, 0);
      if (keep && (wb + pfx) < 32768u) eb_out[wb + pfx] = ed;
    }
    __syncthreads();
    for (int t = tid; t < Npk; t += 1024){
      if (comp[t] == (unsigned short)t && bestv[t] != 0u){
        const unsigned long long ed = eb_in[bestv[t] & 0x3FFFFu];
        const unsigned a = (unsigned)(ed >> 16) & 0xFFFFu;
        const unsigned b = (unsigned)ed & 0xFFFFu;
        const unsigned ra = comp[a], rb = comp[b];
        hook[t] = (unsigned short)((ra == (unsigned)t) ? rb : ra);
      }
    }
    __syncthreads();
    for (int t = tid; t < Npk; t += 1024){
      const unsigned o = hook[t];
      if (o != 0xFFFFu && !(hook[o] == (unsigned short)t && (unsigned)t < o)){
        comp[t] = (unsigned short)o;
        chg_s = 1u;
        const unsigned long long ed = eb_in[bestv[t] & 0x3FFFFu];
        const unsigned pos = atomicAdd(&mcnt_s, 1u);
        if (pos < 4096u) msf[pos] = (((ed >> 32) + 1ULL) << 32) | (ed & 0xFFFFFFFFULL);
      }
    }
    __syncthreads();
    for (;;){
      if (tid == 0) flat_s = 0u;
      __syncthreads();
      for (int t = tid; t < Npk; t += 1024){
        const unsigned c = comp[t];
        const unsigned cc = comp[c];
        if (cc != c){ comp[t] = (unsigned short)cc; flat_s = 1u; }
      }
      __syncthreads();
      if (flat_s == 0u) break;
    }
    const int En = ((int)ecnt2_s < 32768) ? (int)ecnt2_s : 32767;
    const unsigned ch = chg_s;
    __syncthreads();
    Ecur = En;
    { unsigned long long* t2 = eb_in; eb_in = eb_out; eb_out = t2; }
    if (ch == 0u) break;
  }

  const int M = ((int)mcnt_s < 4096) ? (int)mcnt_s : 4095;
  int W = 64; while (W < M) W <<= 1;
  for (int t = M + tid; t < W; t += 1024) msf[t] = 0ULL;
  for (int t = tid; t < Npk; t += 1024) comp[t] = (unsigned short)t;
  __syncthreads();
  for (int k = 2; k <= W; k <<= 1){
    for (int j = k >> 1; j > 0; j >>= 1){
      for (int m2 = tid; m2 < W/2; m2 += 1024){
        const int i = ((m2 & ~(j-1)) << 1) | (m2 & (j-1));
        const int p = i | j;
        const bool up = ((i & k) == 0);
        const unsigned long long a = msf[i], b = msf[p];
        if ((a < b) == up){ msf[i] = b; msf[p] = a; }
      }
      __syncthreads();
    }
  }

  // --- replay: single wave, no inter-chunk flatten (root-identical) ---
  {
    const int nb = (M + 63) >> 6;
    if (tid < 64){
      for (int bch = 0; bch < nb; ++bch){
        const int ei = bch*64 + lane;
        unsigned ra = 0xFFFFu, rb = 0xFFFFu, wgt = 0u;
        if (ei < M){
          const unsigned long long e = msf[ei];
          const unsigned a = ((unsigned)e >> 16) & 0xFFFFu;
          const unsigned b = (unsigned)e & 0xFFFFu;
          wgt = (unsigned)(e >> 32) - 1u;
          ra = uf_find2(comp, a);
          rb = uf_find2(comp, b);
        }
        unsigned kra = 0xFFFFu, krb = 0xFFFFu;
        for (int i = 0; i < 64; ++i){
          const unsigned rai = (unsigned)__builtin_amdgcn_readlane((int)ra, i);
          const unsigned rbi = (unsigned)__builtin_amdgcn_readlane((int)rb, i);
          if (rai == 0xFFFFu || rai == rbi) continue;
          if (lane == i){ kra = rai; krb = rbi; }
          ra = (ra == rai) ? rbi : ra;
          rb = (rb == rai) ? rbi : rb;
        }
        if (kra != 0xFFFFu){
          death[pkrank[kra]] = (unsigned short)wgt;
          comp[kra] = (unsigned short)krb;
        }
      }
    }
    __syncthreads();
  }

  float s = 0.f;
  for (int e = tid; e < NN; e += 1024){
    const int dr = death[e];
    if (dr != 0xFFFF) s += dens[e] - dens[dr];
  }
  red[tid] = s; __syncthreads();
  for (int o = 512; o; o >>= 1){ if (tid < o) red[tid] += red[tid+o]; __syncthreads(); }
  const float S = red[0];

  for (int e8 = 0; e8 < 8; ++e8){
    const int e = tid + e8*1024;
    const int dr = death[e];
    const bool have = (dr != 0xFFFF);
    const unsigned long long bal = __ballot(have);
    const unsigned cnt = (unsigned)__popcll(bal);
    const unsigned pfx = (unsigned)__popcll(bal & ((1ULL << lane) - 1ULL));
    unsigned wb = 0u;
    if (lane == 0 && cnt) wb = atomicAdd(&dcnt_s, cnt);
    wb = (unsigned)__shfl((int)wb, 0);
    if (have && (wb + pfx) < 4096u) dlist[wb + pfx] = ((unsigned)e << 13) | (unsigned)dr;
  }
  __syncthreads();
  const int Dm = ((int)dcnt_s < 4096) ? (int)dcnt_s : 4096;

  // --- top-10 selection: single wave, no barriers, uniform `last` ---
  if (tid < 64){
    unsigned long long last = ~0ULL;
    for (int t10 = 0; t10 < 10; ++t10){
      unsigned long long km = 0ULL;
      for (int i = lane; i < Dm; i += 64){
        const unsigned pk = dlist[i];
        const unsigned e = pk >> 13, dr = pk & 8191u;
        const float pers = dens[e] - dens[dr];
        const unsigned long long k = (((unsigned long long)__float_as_uint(pers)) << 13) | e;
        if (k < last && k > km) km = k;
      }
      for (int off = 32; off; off >>= 1){
        const unsigned long long o = shfl64_xor(km, off);
        km = (o > km) ? o : km;
      }
      if (lane == 0) sel[t10] = km;
      last = km;   // reduce result is wave-uniform
    }
  }
  __syncthreads();
  if (tid == 0){
    float top = 0.f;
    for (int t10 = 0; t10 < 10; ++t10)
      if (sel[t10]) top += __uint_as_float((unsigned)(sel[t10] >> 13));
    float strong = 0.f, dest0 = 0.f, dest1 = 0.f;
    if (sel[0]){
      const unsigned e0 = (unsigned)(sel[0] & 8191ULL);
      dest0 = dens[e0]; dest1 = dens[death[e0]];
    }
    for (int t10 = 1; t10 < 10; ++t10){
      if (!sel[t10]) continue;
      const unsigned e = (unsigned)(sel[t10] & 8191ULL);
      const float a = dens[e] - dest0;
      const float b = dens[death[e]] - dest1;
      strong += sqrtf(a*a + b*b);
    }
    out[0] = (S - top) / 1.41421356237309515f + strong;
  }
}

// =====================================================================
// launch — 7 dispatches (MF path) / 5 (fallback)
// =====================================================================
extern "C" void kernel_launch(void* const* d_in, const int* in_sizes, int n_in,
                              void* d_out, int out_size, void* d_ws, size_t ws_size,
                              hipStream_t stream){
  const float* x = (const float*)d_in[0];
  char* w = (char*)d_ws;
  float*          sq     = (float*)(w + 0);                 // 32KB
  float*          res    = (float*)(w + 32768);             // 32KB
  float*          dens_s = (float*)(w + 65536);             // 32KB
  unsigned short* rank   = (unsigned short*)(w + 98304);    // 16KB
  unsigned short* nn16   = (unsigned short*)(w + 114688);   // 256KB
  unsigned short* ups_t  = (unsigned short*)(w + 376832);   // 256KB (edge ping-pong in k_msf)
  float*          xT     = (float*)(w + 655360);            // 2MB (edges alias after k_samp)
  uint4*          xfrag  = (uint4*)(w + 2752512);           // 1MB
  float*          tub    = (float*)(w + 3801088);           // 32KB
  unsigned char*  nib    = (unsigned char*)(w + 3833856);   // 8MB
  const int use_xt  = (ws_size >= (size_t)2752512) ? 1 : 0;
  const int use_mf2 = (ws_size >= (size_t)(3833856 + 8*1024*1024)) ? 1 : 0;
  unsigned long long* edges = use_xt ? (unsigned long long*)(w + 655360)
                                     : (unsigned long long*)(w + 114688);
  const int edgecap = use_xt ? 262143 : 32767;

  k_pre<<<128, 256, 0, stream>>>(x, xT, sq, use_xt, xfrag, use_mf2);
  if (use_mf2){
    k_samp<true><<<1024, 256, 0, stream>>>(x, xT, sq, tub);
    k_filt<<<1024, 256, 0, stream>>>(x, sq, tub, xfrag, nib);
    k_csort<<<2048, 256, 0, stream>>>(x, sq, tub, nib, res, nn16);
  } else if (use_xt){
    k_cand<true ><<<1024, 256, 0, stream>>>(x, xT, sq, res, nn16);
  } else {
    k_cand<false><<<1024, 256, 0, stream>>>(x, xT, sq, res, nn16);
  }
  k_rank<<<64, 256, 0, stream>>>(res, rank, dens_s);
  k_ups <<<32, 256, 0, stream>>>(rank, nn16, ups_t);
  k_msf <<<1, 1024, 0, stream>>>(dens_s, ups_t, edges, edgecap, (float*)d_out);
}

// Round 8
// 537.354 us; speedup vs baseline: 1.0640x; 1.0640x over previous
//
#include <hip/hip_runtime.h>
#include <stdint.h>

#define NN 8192
#define DD 64
#define POOLCAP 6144

using bf16x8 = __attribute__((ext_vector_type(8))) short;   // 8 bf16 (4 VGPRs)
using f32x4  = __attribute__((ext_vector_type(4))) float;   // MFMA C/D

__device__ __forceinline__ unsigned short f2bf(float f){
  // round-to-nearest-even fp32 -> bf16
  unsigned u = __float_as_uint(f);
  return (unsigned short)((u + 0x7FFFu + ((u >> 16) & 1u)) >> 16);
}

__device__ __forceinline__ unsigned long long shfl64_xor(unsigned long long v, int off){
  return (((unsigned long long)(unsigned)__shfl_xor((int)(v >> 32), off)) << 32)
       | (unsigned long long)(unsigned)__shfl_xor((int)(v & 0xFFFFFFFFu), off);
}

// =====================================================================
// K1: k_pre — transpose + squared norms + bf16 B-fragment build.
// =====================================================================
__global__ __launch_bounds__(256) void k_pre(const float* __restrict__ x, float* __restrict__ xT,
                                             float* __restrict__ sq, int do_tr,
                                             uint4* __restrict__ xfrag, int do_frag){
  __shared__ float tile[64*65];
  const int tid = threadIdx.x;
  const int b = blockIdx.x;
  for (int k = 0; k < 4; ++k){
    const int idx4 = tid + k*256;
    const float4 v = ((const float4*)(x + (size_t)b*4096))[idx4];
    const int row = idx4 >> 4, d0 = (idx4 & 15) * 4;
    tile[row*65 + d0 + 0] = v.x;
    tile[row*65 + d0 + 1] = v.y;
    tile[row*65 + d0 + 2] = v.z;
    tile[row*65 + d0 + 3] = v.w;
  }
  __syncthreads();
  if (do_tr){
    const int jj = tid & 15;
    const int dq = tid >> 4;
    for (int k = 0; k < 4; ++k){
      const int d = dq + 16*k;
      float4 o;
      o.x = tile[(jj*4+0)*65 + d];
      o.y = tile[(jj*4+1)*65 + d];
      o.z = tile[(jj*4+2)*65 + d];
      o.w = tile[(jj*4+3)*65 + d];
      ((float4*)xT)[(size_t)d*2048 + b*16 + jj] = o;
    }
  }
  if (do_frag){
    for (int ch = tid; ch < 512; ch += 256){
      const int c  = ch & 15;
      const int q  = (ch >> 4) & 3;
      const int m  = (ch >> 6) & 1;
      const int gl = ch >> 7;
      const float* sp = tile + (gl*16 + c)*65 + m*32 + q*8;
      unsigned short h[8];
#pragma unroll
      for (int i2 = 0; i2 < 8; ++i2) h[i2] = f2bf(sp[i2]);
      uint4 o;
      o.x = (unsigned)h[0] | ((unsigned)h[1] << 16);
      o.y = (unsigned)h[2] | ((unsigned)h[3] << 16);
      o.z = (unsigned)h[4] | ((unsigned)h[5] << 16);
      o.w = (unsigned)h[6] | ((unsigned)h[7] << 16);
      xfrag[(size_t)b*512 + ch] = o;
    }
  }
  if (tid < 64){
    float acc = 0.f;
    const float* rp = tile + tid*65;
    for (int d = 0; d < 64; ++d) acc = fmaf(rp[d], rp[d], acc);
    sq[b*64 + tid] = acc;
  }
}

// =====================================================================
// exact 1024-col distance pass (bit-exact chain, dims ascending)
// =====================================================================
template<bool XT>
__device__ __forceinline__ void dists_1024(const float* __restrict__ x, const float* __restrict__ xT,
                                           const float* __restrict__ xi, int jbase, int tid,
                                           float acc[8][4]){
#pragma unroll
  for (int r = 0; r < 8; ++r)
#pragma unroll
    for (int q = 0; q < 4; ++q) acc[r][q] = 0.f;
  const int j0 = jbase + tid*4;
  for (int dq = 0; dq < 16; ++dq){
    float4 vj[4];
    if (XT){
#pragma unroll
      for (int s = 0; s < 4; ++s)
        vj[s] = ((const float4*)xT)[(size_t)(dq*4+s)*2048 + (j0 >> 2)];
    } else {
#pragma unroll
      for (int s = 0; s < 4; ++s){
        const int d = dq*4 + s;
        vj[s].x = x[(size_t)(j0+0)*64 + d];
        vj[s].y = x[(size_t)(j0+1)*64 + d];
        vj[s].z = x[(size_t)(j0+2)*64 + d];
        vj[s].w = x[(size_t)(j0+3)*64 + d];
      }
    }
#pragma unroll
    for (int r = 0; r < 8; ++r){
      const float4 wv = ((const float4*)(xi + r*64))[dq];
      acc[r][0] = fmaf(vj[0].x, wv.x, acc[r][0]);
      acc[r][1] = fmaf(vj[0].y, wv.x, acc[r][1]);
      acc[r][2] = fmaf(vj[0].z, wv.x, acc[r][2]);
      acc[r][3] = fmaf(vj[0].w, wv.x, acc[r][3]);
      acc[r][0] = fmaf(vj[1].x, wv.y, acc[r][0]);
      acc[r][1] = fmaf(vj[1].y, wv.y, acc[r][1]);
      acc[r][2] = fmaf(vj[1].z, wv.y, acc[r][2]);
      acc[r][3] = fmaf(vj[1].w, wv.y, acc[r][3]);
      acc[r][0] = fmaf(vj[2].x, wv.z, acc[r][0]);
      acc[r][1] = fmaf(vj[2].y, wv.z, acc[r][1]);
      acc[r][2] = fmaf(vj[2].z, wv.z, acc[r][2]);
      acc[r][3] = fmaf(vj[2].w, wv.z, acc[r][3]);
      acc[r][0] = fmaf(vj[3].x, wv.w, acc[r][0]);
      acc[r][1] = fmaf(vj[3].y, wv.w, acc[r][1]);
      acc[r][2] = fmaf(vj[3].z, wv.w, acc[r][2]);
      acc[r][3] = fmaf(vj[3].w, wv.w, acc[r][3]);
    }
  }
}

// =====================================================================
// K2a: k_samp — exact sampling pass + threshold -> tub[] (global).
// =====================================================================
template<bool XT>
__global__ __launch_bounds__(256) void k_samp(const float* __restrict__ x, const float* __restrict__ xT,
                                              const float* __restrict__ sq, float* __restrict__ tub){
  __shared__ __align__(16) float xi[8*64];
  __shared__ float sqi_s[8];
  __shared__ __align__(16) float samp[8*1024];
  const int tid = threadIdx.x;
  const int i0 = blockIdx.x * 8;
  for (int t = tid; t < 8*64; t += 256) xi[t] = x[(size_t)i0*64 + t];
  if (tid < 8) sqi_s[tid] = sq[i0+tid];
  __syncthreads();
  float sqir[8];
#pragma unroll
  for (int r = 0; r < 8; ++r) sqir[r] = sqi_s[r];

  const int w0 = (blockIdx.x * 1024) & 8191;
  float acc[8][4];
  dists_1024<XT>(x, xT, xi, w0, tid, acc);
  float sqj[4];
#pragma unroll
  for (int q = 0; q < 4; ++q) sqj[q] = sq[w0 + tid*4 + q];
#pragma unroll
  for (int r = 0; r < 8; ++r)
#pragma unroll
    for (int q = 0; q < 4; ++q)
      samp[r*1024 + tid*4 + q] = (sqir[r] + sqj[q]) - 2.f*acc[r][q];
  __syncthreads();
  const int wv = tid >> 6, lane = tid & 63;
  for (int rr = 0; rr < 2; ++rr){
    const int r = wv + rr*4;
    float v[16];
#pragma unroll
    for (int k2 = 0; k2 < 16; ++k2) v[k2] = samp[r*1024 + lane + 64*k2];
    unsigned lo = 0u, hi = 0x7F800001u;
    while (hi - lo > 1u){
      const unsigned mid = (lo + hi) >> 1;
      const float pf = __uint_as_float(mid);
      int c = 0;
#pragma unroll
      for (int k2 = 0; k2 < 16; ++k2) c += (v[k2] < pf) ? 1 : 0;
#pragma unroll
      for (int off = 32; off; off >>= 1) c += __shfl_xor(c, off);
      if (c >= 32) hi = mid; else lo = mid;
    }
    if (lane == 0) tub[i0 + r] = __uint_as_float(hi);
  }
}

// =====================================================================
// K2b: k_filt — pure MFMA bf16 margin filter (unchanged, verified).
// =====================================================================
__global__ __launch_bounds__(256) void k_filt(const float* __restrict__ x, const float* __restrict__ sq,
                                              const float* __restrict__ tub,
                                              const uint4* __restrict__ xfrag,
                                              unsigned char* __restrict__ nib){
  const int tid = threadIdx.x;
  const int l   = tid & 63;
  const int w   = tid >> 6;        // wave id 0..3
  const int qh  = l >> 4;          // K-group (input) / row-group (output)
  const int c16 = l & 15;          // A-row (input) / col (output)
  const int i0  = blockIdx.x * 8;

  bf16x8 a0, a1;
#pragma unroll
  for (int i2 = 0; i2 < 8; ++i2){ a0[i2] = 0; a1[i2] = 0; }
  if (c16 < 8){
    const float* ap = x + (size_t)(i0 + c16)*64 + qh*8;
#pragma unroll
    for (int i2 = 0; i2 < 8; ++i2){
      a0[i2] = (short)f2bf(ap[i2]);
      a1[i2] = (short)f2bf(ap[i2 + 32]);
    }
  }
  float thr3[4], rs[4];
#pragma unroll
  for (int rg = 0; rg < 4; ++rg){
    int row = qh*4 + rg; row = (row < 8) ? row : 0;
    thr3[rg] = (tub[i0 + row] - sq[i0 + row]) + 0.002f;
    rs[rg]   = 0.017f * sqrtf(sq[i0 + row]);
  }

  const bf16x8* bfp = (const bf16x8*)xfrag + (size_t)w*128 + l;
  const float*  sqp = sq + w*16 + c16;
  unsigned char* nb = nib + (size_t)blockIdx.x*8192 + w*16 + c16;

  bf16x8 A0 = bfp[0],   A1 = bfp[64];     float SA = sqp[0];
  bf16x8 B0 = bfp[512], B1 = bfp[512+64]; float SB = sqp[64];
  for (int it = 0; it < 128; it += 2){
    const int n2 = (it+2 < 128) ? it+2 : 126;
    const int n3 = (it+3 < 128) ? it+3 : 127;
    bf16x8 N0 = bfp[(size_t)n2*512], N1 = bfp[(size_t)n2*512 + 64];
    bf16x8 M0 = bfp[(size_t)n3*512], M1 = bfp[(size_t)n3*512 + 64];
    const float SN = sqp[n2*64], SM = sqp[n3*64];
    {
      f32x4 acc = {0.f, 0.f, 0.f, 0.f};
      acc = __builtin_amdgcn_mfma_f32_16x16x32_bf16(a0, A0, acc, 0, 0, 0);
      acc = __builtin_amdgcn_mfma_f32_16x16x32_bf16(a1, A1, acc, 0, 0, 0);
      const float sr = sqrtf(SA);
      unsigned m4 = 0u;
      m4 |= (fmaf(-rs[0], sr, fmaf(-2.f, acc[0], SA)) < thr3[0]) ? 1u : 0u;
      m4 |= (fmaf(-rs[1], sr, fmaf(-2.f, acc[1], SA)) < thr3[1]) ? 2u : 0u;
      m4 |= (fmaf(-rs[2], sr, fmaf(-2.f, acc[2], SA)) < thr3[2]) ? 4u : 0u;
      m4 |= (fmaf(-rs[3], sr, fmaf(-2.f, acc[3], SA)) < thr3[3]) ? 8u : 0u;
      const unsigned pm = (unsigned)__shfl((int)m4, (l + 16) & 63);
      if (l < 16) nb[it*64] = (unsigned char)(m4 | (pm << 4));
    }
    {
      f32x4 acc = {0.f, 0.f, 0.f, 0.f};
      acc = __builtin_amdgcn_mfma_f32_16x16x32_bf16(a0, B0, acc, 0, 0, 0);
      acc = __builtin_amdgcn_mfma_f32_16x16x32_bf16(a1, B1, acc, 0, 0, 0);
      const float sr = sqrtf(SB);
      unsigned m4 = 0u;
      m4 |= (fmaf(-rs[0], sr, fmaf(-2.f, acc[0], SB)) < thr3[0]) ? 1u : 0u;
      m4 |= (fmaf(-rs[1], sr, fmaf(-2.f, acc[1], SB)) < thr3[1]) ? 2u : 0u;
      m4 |= (fmaf(-rs[2], sr, fmaf(-2.f, acc[2], SB)) < thr3[2]) ? 4u : 0u;
      m4 |= (fmaf(-rs[3], sr, fmaf(-2.f, acc[3], SB)) < thr3[3]) ? 8u : 0u;
      const unsigned pm = (unsigned)__shfl((int)m4, (l + 16) & 63);
      if (l < 16) nb[(it+1)*64] = (unsigned char)(m4 | (pm << 4));
    }
    A0 = N0; A1 = N1; SA = SN;
    B0 = M0; B1 = M1; SB = SM;
  }
}

// =====================================================================
// K2c: k_csort — 1024 blocks x 8 rows. NEW Phase A: bitmap -> LDS pool
// (wave-aggregated offsets), then 2-lane relay recompute with fully
// COALESCED row loads (lanes 2c/2c+1 read the two 128B halves of row j;
// exact chain runs stage0 dims 0..31 on even lane, shfl acc, stage1
// dims 32..63 on odd lane — identical fmaf sequence => bit-exact).
// Phase B: verified wave-local top-64 selection (2 rows/wave).
// =====================================================================
__global__ __launch_bounds__(256, 4) void k_csort(const float* __restrict__ x, const float* __restrict__ sq,
                                                  const float* __restrict__ tub,
                                                  const unsigned char* __restrict__ nib,
                                                  float* __restrict__ res, unsigned short* __restrict__ nn16){
  __shared__ __align__(16) float xi[8*68];     // padded stride 68
  __shared__ float sqi_s[8];
  __shared__ float tubs[8];
  __shared__ __align__(16) unsigned long long cand[8*512];   // 32KB
  __shared__ unsigned ccnt[8];
  __shared__ __align__(16) unsigned short pool[POOLCAP];     // 12KB
  __shared__ unsigned pcnt_s;
  const int tid  = threadIdx.x;
  const int lane = tid & 63;
  const int w    = tid >> 6;
  const int grp  = blockIdx.x;
  const int i0   = grp*8;

  for (int t = tid; t < 8*64; t += 256) xi[(t >> 6)*68 + (t & 63)] = x[(size_t)i0*64 + t];
  if (tid < 8){ sqi_s[tid] = sq[i0+tid]; tubs[tid] = tub[i0+tid]; ccnt[tid] = 0u; }
  if (tid == 0) pcnt_s = 0u;
  for (int t = tid; t < 8*512; t += 256) cand[t] = ~0ULL;
  __syncthreads();

  // ---- Phase A1: scan bitmap -> pool (wave-aggregated offsets) ----
  {
    const uint4* nb4 = (const uint4*)(nib + (size_t)grp*8192);
    const uint4 vA = nb4[tid];
    const uint4 vB = nb4[tid + 256];
    unsigned wds[8] = {vA.x, vA.y, vA.z, vA.w, vB.x, vB.y, vB.z, vB.w};
    int cnt = 0;
#pragma unroll
    for (int ww = 0; ww < 8; ++ww) cnt += __popc(wds[ww]);
    int incl = cnt;
    for (int s = 1; s < 64; s <<= 1){
      const int o = __shfl_up(incl, s);
      if (lane >= s) incl += o;
    }
    const unsigned tot = (unsigned)__shfl(incl, 63);
    unsigned wb = 0u;
    if (lane == 0 && tot) wb = atomicAdd(&pcnt_s, tot);
    wb = (unsigned)__shfl((int)wb, 0);
    int myoff = (int)wb + incl - cnt;
#pragma unroll
    for (int ww = 0; ww < 8; ++ww){
      const int u = (ww < 4) ? tid : tid + 256;
      const int colbase = u*16 + (ww & 3)*4;
      unsigned wvv = wds[ww];
      while (wvv){
        const int bit = __builtin_ctz(wvv);
        wvv &= wvv - 1u;
        const int r = bit & 7;
        const int j = colbase + (bit >> 3);
        if (myoff < POOLCAP){
          pool[myoff] = (unsigned short)((r << 13) | j);
        } else {
          // overflow fallback: inline exact path (never expected; correctness-preserving)
          const float* xj = x + (size_t)j*64;
          const float* xr = xi + r*68;
          float acc = 0.f;
#pragma unroll
          for (int d4 = 0; d4 < 16; ++d4){
            const float4 a = ((const float4*)xj)[d4];
            const float4 b = ((const float4*)xr)[d4];
            acc = fmaf(a.x, b.x, acc);
            acc = fmaf(a.y, b.y, acc);
            acc = fmaf(a.z, b.z, acc);
            acc = fmaf(a.w, b.w, acc);
          }
          const float dist = (sqi_s[r] + sq[j]) - 2.f*acc;
          if (dist < tubs[r]){
            const unsigned pos = atomicAdd(&ccnt[r], 1u);
            if (pos < 512u){
              unsigned u2 = __float_as_uint(dist);
              u2 = ((int)u2 < 0) ? ~u2 : (u2 | 0x80000000u);
              cand[r*512 + pos] = (((unsigned long long)u2) << 13) | (unsigned)j;
            }
          }
        }
        ++myoff;
      }
    }
  }
  __syncthreads();
  const int P = ((int)pcnt_s < POOLCAP) ? (int)pcnt_s : POOLCAP;

  // ---- Phase A2: 2-lane relay recompute (coalesced row loads) ----
  {
    const int c  = lane >> 1;      // candidate slot within pass (0..31)
    const int k2 = lane & 1;       // row-half (0: dims 0..31, 1: dims 32..63)
    for (int base = w*32; base < P; base += 128){
      const int ci = base + c;
      const bool valid = ci < P;
      const unsigned e = valid ? (unsigned)pool[ci] : 0u;
      const int j = (int)(e & 8191u);
      const int r = (int)(e >> 13);
      const float4* xj = (const float4*)(x + (size_t)j*64 + k2*32);
      const float4* xr = (const float4*)(xi + r*68 + k2*32);
      float4 vv[8];
#pragma unroll
      for (int d4 = 0; d4 < 8; ++d4) vv[d4] = xj[d4];
      float acc = 0.f;
      if (k2 == 0){
#pragma unroll
        for (int d4 = 0; d4 < 8; ++d4){
          const float4 a = vv[d4], b = xr[d4];
          acc = fmaf(a.x, b.x, acc);
          acc = fmaf(a.y, b.y, acc);
          acc = fmaf(a.z, b.z, acc);
          acc = fmaf(a.w, b.w, acc);
        }
      }
      const float passed = __shfl_xor(acc, 1);
      if (k2 == 1){
        acc = passed;
#pragma unroll
        for (int d4 = 0; d4 < 8; ++d4){
          const float4 a = vv[d4], b = xr[d4];
          acc = fmaf(a.x, b.x, acc);
          acc = fmaf(a.y, b.y, acc);
          acc = fmaf(a.z, b.z, acc);
          acc = fmaf(a.w, b.w, acc);
        }
        if (valid){
          const float dist = (sqi_s[r] + sq[j]) - 2.f*acc;
          if (dist < tubs[r]){
            const unsigned pos = atomicAdd(&ccnt[r], 1u);
            if (pos < 512u){
              unsigned u2 = __float_as_uint(dist);
              u2 = ((int)u2 < 0) ? ~u2 : (u2 | 0x80000000u);
              cand[r*512 + pos] = (((unsigned long long)u2) << 13) | (unsigned)j;
            }
          }
        }
      }
    }
  }
  __syncthreads();

  // ---- Phase B: per-wave exact top-64 selection + sort (verified) ----
  for (int rr = 0; rr < 2; ++rr){
    const int r = w + rr*4;
    unsigned long long k8[8];
#pragma unroll
    for (int t = 0; t < 8; ++t) k8[t] = cand[r*512 + lane + 64*t];

    const unsigned long long REALMAX = (1ULL << 45) - 1ULL;
    int creal = 0;
#pragma unroll
    for (int t = 0; t < 8; ++t) creal += (int)__popcll(__ballot(k8[t] <= REALMAX));

    unsigned long long K50;
    if (creal >= 50){
      unsigned long long lo = 0ULL, hi = REALMAX;
      while (lo < hi){
        const unsigned long long mid = lo + ((hi - lo) >> 1);
        int c = 0;
#pragma unroll
        for (int t = 0; t < 8; ++t) c += (int)__popcll(__ballot(k8[t] <= mid));
        if (c >= 50) hi = mid; else lo = mid + 1ULL;
      }
      K50 = hi;
    } else {
      K50 = ~0ULL;
    }

    unsigned long long* buf = cand + r*512;
    buf[lane] = ~0ULL;
    int base = 0;
#pragma unroll
    for (int t = 0; t < 8; ++t){
      const bool pr = (k8[t] <= K50) && (k8[t] != ~0ULL);
      const unsigned long long bal = __ballot(pr);
      const int off = base + (int)__popcll(bal & ((1ULL << lane) - 1ULL));
      if (pr && off < 64) buf[off] = k8[t];
      base += (int)__popcll(bal);
    }
    unsigned long long key = buf[lane];

#pragma unroll
    for (int k = 2; k <= 64; k <<= 1){
#pragma unroll
      for (int j = k >> 1; j > 0; j >>= 1){
        const unsigned long long p = shfl64_xor(key, j);
        const bool dirUp = ((lane & k) == 0);
        const bool lower = ((lane & j) == 0);
        const unsigned long long mn = (key < p) ? key : p;
        const unsigned long long mx = (key < p) ? p : key;
        key = (dirUp == lower) ? mn : mx;
      }
    }

    float e = 0.f;
    if (lane < 50){
      unsigned u2 = (unsigned)(key >> 13);
      u2 = (u2 & 0x80000000u) ? (u2 & 0x7FFFFFFFu) : ~u2;
      e = expf(-__uint_as_float(u2) / 30.f);
    }
#pragma unroll
    for (int off = 32; off; off >>= 1) e += __shfl_down(e, off);
    if (lane == 0) res[i0+r] = e / 1500.f;
    if (lane < 16) nn16[(size_t)(i0+r)*16 + lane] = (unsigned short)(key & 8191ULL);
  }
}

// =====================================================================
// K2 (fallback): original exact k_cand (round-0 proven path).
// =====================================================================
template<bool XT>
__global__ __launch_bounds__(256) void k_cand(const float* __restrict__ x, const float* __restrict__ xT,
                                              const float* __restrict__ sq,
                                              float* __restrict__ res, unsigned short* __restrict__ nn16){
  __shared__ float xi[8*64];
  __shared__ float sqi_s[8];
  __shared__ float tubs[8];
  __shared__ __align__(16) unsigned long long cand[8*512];
  __shared__ unsigned ccnt[8];
  float* samp = (float*)cand;
  const int tid = threadIdx.x;
  const int i0 = blockIdx.x * 8;
  for (int t = tid; t < 8*64; t += 256) xi[t] = x[(size_t)i0*64 + t];
  if (tid < 8){ sqi_s[tid] = sq[i0+tid]; ccnt[tid] = 0u; }
  __syncthreads();
  float sqir[8];
#pragma unroll
  for (int r = 0; r < 8; ++r) sqir[r] = sqi_s[r];

  const int w0 = (blockIdx.x * 1024) & 8191;
  {
    float acc[8][4];
    dists_1024<XT>(x, xT, xi, w0, tid, acc);
    float sqj[4];
#pragma unroll
    for (int q = 0; q < 4; ++q) sqj[q] = sq[w0 + tid*4 + q];
#pragma unroll
    for (int r = 0; r < 8; ++r)
#pragma unroll
      for (int q = 0; q < 4; ++q)
        samp[r*1024 + tid*4 + q] = (sqir[r] + sqj[q]) - 2.f*acc[r][q];
  }
  __syncthreads();
  {
    const int wv = tid >> 6, lane = tid & 63;
    for (int rr = 0; rr < 2; ++rr){
      const int r = wv + rr*4;
      float v[16];
#pragma unroll
      for (int k2 = 0; k2 < 16; ++k2) v[k2] = samp[r*1024 + lane + 64*k2];
      unsigned lo = 0u, hi = 0x7F800001u;
      while (hi - lo > 1u){
        const unsigned mid = (lo + hi) >> 1;
        const float pf = __uint_as_float(mid);
        int c = 0;
#pragma unroll
        for (int k2 = 0; k2 < 16; ++k2) c += (v[k2] < pf) ? 1 : 0;
#pragma unroll
        for (int off = 32; off; off >>= 1) c += __shfl_xor(c, off);
        if (c >= 32) hi = mid; else lo = mid;
      }
      if (lane == 0) tubs[r] = __uint_as_float(hi);
    }
  }
  __syncthreads();
  float tubr[8];
#pragma unroll
  for (int r = 0; r < 8; ++r) tubr[r] = tubs[r];
  for (int t = tid; t < 8*512; t += 256) cand[t] = ~0ULL;
  __syncthreads();

  for (int pass = 0; pass < 8; ++pass){
    const int jb = pass*1024;
    float acc[8][4];
    dists_1024<XT>(x, xT, xi, jb, tid, acc);
    const int j0 = jb + tid*4;
    float sqj[4];
#pragma unroll
    for (int q = 0; q < 4; ++q) sqj[q] = sq[j0 + q];
#pragma unroll
    for (int r = 0; r < 8; ++r){
#pragma unroll
      for (int q = 0; q < 4; ++q){
        const float dist = (sqir[r] + sqj[q]) - 2.f*acc[r][q];
        if (dist < tubr[r]){
          const unsigned pos = atomicAdd(&ccnt[r], 1u);
          if (pos < 512u){
            unsigned u = __float_as_uint(dist);
            u = ((int)u < 0) ? ~u : (u | 0x80000000u);
            cand[r*512 + pos] = (((unsigned long long)u) << 13) | (unsigned)(j0 + q);
          }
        }
      }
    }
  }
  __syncthreads();

  for (int k = 2; k <= 512; k <<= 1){
    for (int jj2 = k >> 1; jj2 > 0; jj2 >>= 1){
      const int mm = tid;
      const int i = ((mm & ~(jj2-1)) << 1) | (mm & (jj2-1));
      const int p = i | jj2;
      const bool up2 = ((i & k) == 0);
#pragma unroll
      for (int r = 0; r < 8; ++r){
        unsigned long long a = cand[r*512+i], bb = cand[r*512+p];
        if ((a > bb) == up2){ cand[r*512+i] = bb; cand[r*512+p] = a; }
      }
      __syncthreads();
    }
  }

  const int wv2 = tid >> 6, lane2 = tid & 63;
  for (int rr = 0; rr < 2; ++rr){
    const int r = wv2*2 + rr;
    const unsigned long long kk = cand[r*512 + lane2];
    float e = 0.f;
    if (lane2 < 50){
      unsigned u2 = (unsigned)(kk >> 13);
      u2 = (u2 & 0x80000000u) ? (u2 & 0x7FFFFFFFu) : ~u2;
      e = expf(-__uint_as_float(u2) / 30.f);
    }
#pragma unroll
    for (int off = 32; off; off >>= 1) e += __shfl_down(e, off);
    if (lane2 == 0) res[i0+r] = e / 1500.f;
    if (lane2 < 16) nn16[(size_t)(i0+r)*16 + lane2] = (unsigned short)(kk & 8191ULL);
  }
}

// =====================================================================
// K3: k_rank — unchanged.
// =====================================================================
__global__ __launch_bounds__(256) void k_rank(const float* __restrict__ res,
                                              unsigned short* __restrict__ rank,
                                              float* __restrict__ dens_s){
  __shared__ __align__(16) unsigned long long keys[NN]; // 64KB
  __shared__ float red[256];
  __shared__ unsigned short pcnt[256];
  const int tid = threadIdx.x;
  float m = 0.f;
  for (int t = tid; t < NN; t += 256) m = fmaxf(m, res[t]);
  red[tid] = m; __syncthreads();
  for (int o = 128; o; o >>= 1){ if (tid < o) red[tid] = fmaxf(red[tid], red[tid+o]); __syncthreads(); }
  const float mr = red[0];
  __syncthreads();
  for (int t = tid; t < NN; t += 256){
    const float dnv = res[t] / mr;
    keys[t] = (((unsigned long long)__float_as_uint(dnv)) << 13) | (unsigned)t;
  }
  __syncthreads();
  const int i = blockIdx.x*128 + (tid & 127);
  const unsigned long long ki = keys[i];
  const int j0 = (tid >> 7) * (NN/2);      // wave-uniform half-split
  int c = 0;
#pragma unroll 8
  for (int j = 0; j < NN/2; ++j) c += (keys[j0 + j] < ki) ? 1 : 0;
  pcnt[tid] = (unsigned short)c;
  __syncthreads();
  if (tid < 128){
    const int r = (int)pcnt[tid] + (int)pcnt[tid + 128];
    rank[i] = (unsigned short)r;
    dens_s[r] = __uint_as_float((unsigned)(ki >> 13));   // bit-identical scatter
  }
}

// =====================================================================
// K4: k_ups — unchanged.
// =====================================================================
__global__ __launch_bounds__(256) void k_ups(const unsigned short* __restrict__ rank,
                                             const unsigned short* __restrict__ nn16,
                                             unsigned short* __restrict__ ups_t){
  __shared__ __align__(16) unsigned short rk[NN]; // 16KB
  const int tid = threadIdx.x;
  for (int t = tid; t < NN/8; t += 256) ((uint4*)rk)[t] = ((const uint4*)rank)[t];
  __syncthreads();
  const int o = blockIdx.x*256 + tid;
  const int p = rk[o];
  const uint4 n0 = ((const uint4*)nn16)[(size_t)o*2];
  const uint4 n1 = ((const uint4*)nn16)[(size_t)o*2 + 1];
  unsigned nw[8] = {n0.x, n0.y, n0.z, n0.w, n1.x, n1.y, n1.z, n1.w};
  unsigned short outv[16];
  int cnt = 0;
  for (int k = 0; k < 16; ++k){
    const unsigned nb = (nw[k >> 1] >> ((k & 1) * 16)) & 0xFFFFu;
    const unsigned r = rk[nb];
    if ((int)r > p){
      int q = cnt++;
      while (q > 0 && outv[q-1] < (unsigned short)r){ outv[q] = outv[q-1]; --q; }
      outv[q] = (unsigned short)r;
    }
  }
  for (int k = cnt; k < 16; ++k) outv[k] = 0;
  unsigned short* dst = ups_t + (size_t)p*16;
  uint4 a, b;
  a.x = (unsigned)outv[0] | ((unsigned)outv[1] << 16);
  a.y = (unsigned)outv[2] | ((unsigned)outv[3] << 16);
  a.z = (unsigned)outv[4] | ((unsigned)outv[5] << 16);
  a.w = (unsigned)outv[6] | ((unsigned)outv[7] << 16);
  b.x = (unsigned)outv[8] | ((unsigned)outv[9] << 16);
  b.y = (unsigned)outv[10] | ((unsigned)outv[11] << 16);
  b.z = (unsigned)outv[12] | ((unsigned)outv[13] << 16);
  b.w = (unsigned)outv[14] | ((unsigned)outv[15] << 16);
  ((uint4*)dst)[0] = a;
  ((uint4*)dst)[1] = b;
}

// =====================================================================
// K5: k_msf — Boruvka-MSF + replay (round-5/6 verified).
// =====================================================================
__device__ __forceinline__ unsigned uf_find2(volatile unsigned short* comp, unsigned x){
  unsigned r = comp[x];
  while (true){
    const unsigned g = comp[r];
    if (g == r) break;
    comp[x] = (unsigned short)g;
    x = r; r = g;
  }
  return r;
}

__global__ __launch_bounds__(1024) void k_msf(const float* __restrict__ dens_s,
                                              unsigned short* __restrict__ ups_t,
                                              unsigned long long* __restrict__ edges,
                                              int edgecap,
                                              float* __restrict__ out){
  __shared__ __align__(16) float dens[NN];              // 32KB
  __shared__ __align__(16) unsigned short P[NN];        // 16KB
  __shared__ __align__(16) unsigned short pkid[NN];     // 16KB
  __shared__ __align__(16) unsigned short death[NN];    // 16KB
  __shared__ __align__(16) unsigned short pkrank[4096]; // 8KB
  __shared__ __align__(16) unsigned short comp[4096];   // 8KB
  __shared__ __align__(16) unsigned short hook[4096];   // 8KB
  __shared__ __align__(16) unsigned bestv[4096];        // 16KB
  __shared__ __align__(16) unsigned long long msf[4096];// 32KB
  __shared__ unsigned long long sel[10];
  __shared__ unsigned ecnt_s, ecnt2_s, mcnt_s, chg_s, flat_s, dcnt_s;
  unsigned* scan1 = (unsigned*)msf;
  float* red = (float*)msf;
  unsigned* dlist = bestv;

  const int tid = threadIdx.x;
  const int lane = tid & 63;

  for (int t = tid; t < NN/4; t += 1024)
    ((float4*)dens)[t] = ((const float4*)dens_s)[t];
  for (int t = tid; t < NN; t += 1024){
    const unsigned u0 = ups_t[(size_t)t*16];
    P[t] = (u0 == 0u) ? (unsigned short)t : (unsigned short)u0;
    death[t] = 0xFFFFu;
  }
  if (tid == 0){ ecnt_s = 0u; mcnt_s = 0u; dcnt_s = 0u; }
  __syncthreads();

  for (int rd = 0; rd < 13; ++rd){
    for (int pp = 0; pp < 8; ++pp){
      const int p = tid + pp*1024;
      const unsigned v = P[p];
      const unsigned w2 = P[v];
      if (w2 != v) P[p] = (unsigned short)w2;
    }
    __syncthreads();
  }

  // --- peak-id scan: wave shfl scan + 16-wave-sum scan (2 barriers) ---
  {
    const int p0 = tid*8;
    int c = 0;
    for (int k = 0; k < 8; ++k) c += (P[p0+k] == (unsigned short)(p0+k)) ? 1 : 0;
    unsigned v = (unsigned)c;
    for (int s = 1; s < 64; s <<= 1){
      const unsigned o = (unsigned)__shfl_up((int)v, s);
      if (lane >= s) v += o;
    }
    if (lane == 63) scan1[1024 + (tid >> 6)] = v;      // wave totals
    __syncthreads();
    if (tid < 16){
      unsigned wv2 = scan1[1024 + tid];
      for (int s = 1; s < 16; s <<= 1){
        const unsigned o = (unsigned)__shfl_up((int)wv2, s);
        if (tid >= s) wv2 += o;
      }
      scan1[1040 + tid] = wv2;                         // inclusive wave prefix
    }
    __syncthreads();
    const unsigned woff = (tid >= 64) ? scan1[1040 + (tid >> 6) - 1] : 0u;
    const unsigned incl = v + woff;
    if (tid == 1023) scan1[1023] = incl;               // block total
    int base = (int)incl - c;
    for (int k = 0; k < 8; ++k){
      const int p = p0 + k;
      if (P[p] == (unsigned short)p){
        pkid[p] = (unsigned short)base;
        if (base < 4096) pkrank[base] = (unsigned short)p;
        ++base;
      }
    }
  }
  __syncthreads();
  int Npk = (int)scan1[1023];
  if (Npk > 4096) Npk = 4096;
  __syncthreads();

  for (int pp = 0; pp < 8; ++pp){
    const int p = tid + pp*1024;
    const uint4 a4 = ((const uint4*)ups_t)[(size_t)p*2];
    const uint4 b4 = ((const uint4*)ups_t)[(size_t)p*2 + 1];
    unsigned uu[8] = {a4.x, a4.y, a4.z, a4.w, b4.x, b4.y, b4.z, b4.w};
    unsigned edv[15];
    int nd = 0;
    const unsigned u0 = uu[0] & 0xFFFFu;
    if (u0 != 0u){
      const unsigned m0 = P[u0];
      const unsigned m0id = pkid[m0];
      for (int k = 1; k < 16; ++k){
        const unsigned uk = (uu[k >> 1] >> ((k & 1) * 16)) & 0xFFFFu;
        if (uk == 0u) break;
        const unsigned v = P[uk];
        if (v == m0) continue;
        const unsigned vid = pkid[v];
        bool dup = false;
        for (int j = 0; j < nd; ++j) dup = dup || ((edv[j] >> 16) == vid);
        if (dup) continue;
        edv[nd++] = (vid << 16) | m0id;
      }
    }
    unsigned off = (unsigned)nd;
    for (int s = 1; s < 64; s <<= 1){
      const unsigned o = (unsigned)__shfl_up((int)off, s);
      if (lane >= s) off += o;
    }
    const unsigned tot = (unsigned)__shfl((int)off, 63);
    unsigned wb = 0u;
    if (lane == 0 && tot) wb = atomicAdd(&ecnt_s, tot);
    wb = (unsigned)__shfl((int)wb, 0);
    const unsigned mybase = wb + off - (unsigned)nd;
    for (int k = 0; k < nd; ++k){
      const unsigned pos = mybase + (unsigned)k;
      if ((int)pos < edgecap)
        edges[pos] = (((unsigned long long)(unsigned)p) << 32) | (unsigned long long)edv[k];
    }
  }
  __syncthreads();
  int Ecur = ((int)ecnt_s < edgecap) ? (int)ecnt_s : edgecap;

  unsigned long long* eb_in  = edges;
  unsigned long long* eb_out = (unsigned long long*)ups_t;
  for (int t = tid; t < Npk; t += 1024) comp[t] = (unsigned short)t;
  __syncthreads();
  for (int round = 0; round < 16 && Ecur > 0; ++round){
    for (int t = tid; t < Npk; t += 1024){ bestv[t] = 0u; hook[t] = 0xFFFFu; }
    if (tid == 0){ chg_s = 0u; ecnt2_s = 0u; }
    __syncthreads();
    for (int base = 0; base < Ecur; base += 1024){
      const int e = base + tid;
      bool keep = false;
      unsigned long long ed = 0ULL;
      if (e < Ecur){
        ed = eb_in[e];
        const unsigned a = (unsigned)(ed >> 16) & 0xFFFFu;
        const unsigned b = (unsigned)ed & 0xFFFFu;
        const unsigned ra = comp[a], rb = comp[b];
        if (ra != rb){
          keep = true;
          const unsigned key = ((((unsigned)(ed >> 32)) + 1u) << 18) | (unsigned)e;
          atomicMax(&bestv[ra], key);
          atomicMax(&bestv[rb], key);
        }
      }
      const unsigned long long bal = __ballot(keep);
      const unsigned cnt = (unsigned)__popcll(bal);
      const unsigned pfx = (unsigned)__popcll(bal & ((1ULL << lane) - 1ULL));
      unsigned wb = 0u;
      if (lane == 0 && cnt) wb = atomicAdd(&ecnt2_s, cnt);
      wb = (unsigned)__shfl((int)wb, 0);
      if (keep && (wb + pfx) < 32768u) eb_out[wb + pfx] = ed;
    }
    __syncthreads();
    for (int t = tid; t < Npk; t += 1024){
      if (comp[t] == (unsigned short)t && bestv[t] != 0u){
        const unsigned long long ed = eb_in[bestv[t] & 0x3FFFFu];
        const unsigned a = (unsigned)(ed >> 16) & 0xFFFFu;
        const unsigned b = (unsigned)ed & 0xFFFFu;
        const unsigned ra = comp[a], rb = comp[b];
        hook[t] = (unsigned short)((ra == (unsigned)t) ? rb : ra);
      }
    }
    __syncthreads();
    for (int t = tid; t < Npk; t += 1024){
      const unsigned o = hook[t];
      if (o != 0xFFFFu && !(hook[o] == (unsigned short)t && (unsigned)t < o)){
        comp[t] = (unsigned short)o;
        chg_s = 1u;
        const unsigned long long ed = eb_in[bestv[t] & 0x3FFFFu];
        const unsigned pos = atomicAdd(&mcnt_s, 1u);
        if (pos < 4096u) msf[pos] = (((ed >> 32) + 1ULL) << 32) | (ed & 0xFFFFFFFFULL);
      }
    }
    __syncthreads();
    for (;;){
      if (tid == 0) flat_s = 0u;
      __syncthreads();
      for (int t = tid; t < Npk; t += 1024){
        const unsigned c = comp[t];
        const unsigned cc = comp[c];
        if (cc != c){ comp[t] = (unsigned short)cc; flat_s = 1u; }
      }
      __syncthreads();
      if (flat_s == 0u) break;
    }
    const int En = ((int)ecnt2_s < 32768) ? (int)ecnt2_s : 32767;
    const unsigned ch = chg_s;
    __syncthreads();
    Ecur = En;
    { unsigned long long* t2 = eb_in; eb_in = eb_out; eb_out = t2; }
    if (ch == 0u) break;
  }

  const int M = ((int)mcnt_s < 4096) ? (int)mcnt_s : 4095;
  int W = 64; while (W < M) W <<= 1;
  for (int t = M + tid; t < W; t += 1024) msf[t] = 0ULL;
  for (int t = tid; t < Npk; t += 1024) comp[t] = (unsigned short)t;
  __syncthreads();
  for (int k = 2; k <= W; k <<= 1){
    for (int j = k >> 1; j > 0; j >>= 1){
      for (int m2 = tid; m2 < W/2; m2 += 1024){
        const int i = ((m2 & ~(j-1)) << 1) | (m2 & (j-1));
        const int p = i | j;
        const bool up = ((i & k) == 0);
        const unsigned long long a = msf[i], b = msf[p];
        if ((a < b) == up){ msf[i] = b; msf[p] = a; }
      }
      __syncthreads();
    }
  }

  // --- replay: single wave, no inter-chunk flatten (root-identical) ---
  {
    const int nb = (M + 63) >> 6;
    if (tid < 64){
      for (int bch = 0; bch < nb; ++bch){
        const int ei = bch*64 + lane;
        unsigned ra = 0xFFFFu, rb = 0xFFFFu, wgt = 0u;
        if (ei < M){
          const unsigned long long e = msf[ei];
          const unsigned a = ((unsigned)e >> 16) & 0xFFFFu;
          const unsigned b = (unsigned)e & 0xFFFFu;
          wgt = (unsigned)(e >> 32) - 1u;
          ra = uf_find2(comp, a);
          rb = uf_find2(comp, b);
        }
        unsigned kra = 0xFFFFu, krb = 0xFFFFu;
        for (int i = 0; i < 64; ++i){
          const unsigned rai = (unsigned)__builtin_amdgcn_readlane((int)ra, i);
          const unsigned rbi = (unsigned)__builtin_amdgcn_readlane((int)rb, i);
          if (rai == 0xFFFFu || rai == rbi) continue;
          if (lane == i){ kra = rai; krb = rbi; }
          ra = (ra == rai) ? rbi : ra;
          rb = (rb == rai) ? rbi : rb;
        }
        if (kra != 0xFFFFu){
          death[pkrank[kra]] = (unsigned short)wgt;
          comp[kra] = (unsigned short)krb;
        }
      }
    }
    __syncthreads();
  }

  float s = 0.f;
  for (int e = tid; e < NN; e += 1024){
    const int dr = death[e];
    if (dr != 0xFFFF) s += dens[e] - dens[dr];
  }
  red[tid] = s; __syncthreads();
  for (int o = 512; o; o >>= 1){ if (tid < o) red[tid] += red[tid+o]; __syncthreads(); }
  const float S = red[0];

  for (int e8 = 0; e8 < 8; ++e8){
    const int e = tid + e8*1024;
    const int dr = death[e];
    const bool have = (dr != 0xFFFF);
    const unsigned long long bal = __ballot(have);
    const unsigned cnt = (unsigned)__popcll(bal);
    const unsigned pfx = (unsigned)__popcll(bal & ((1ULL << lane) - 1ULL));
    unsigned wb = 0u;
    if (lane == 0 && cnt) wb = atomicAdd(&dcnt_s, cnt);
    wb = (unsigned)__shfl((int)wb, 0);
    if (have && (wb + pfx) < 4096u) dlist[wb + pfx] = ((unsigned)e << 13) | (unsigned)dr;
  }
  __syncthreads();
  const int Dm = ((int)dcnt_s < 4096) ? (int)dcnt_s : 4096;

  // --- top-10 selection: single wave, no barriers, uniform `last` ---
  if (tid < 64){
    unsigned long long last = ~0ULL;
    for (int t10 = 0; t10 < 10; ++t10){
      unsigned long long km = 0ULL;
      for (int i = lane; i < Dm; i += 64){
        const unsigned pk = dlist[i];
        const unsigned e = pk >> 13, dr = pk & 8191u;
        const float pers = dens[e] - dens[dr];
        const unsigned long long k = (((unsigned long long)__float_as_uint(pers)) << 13) | e;
        if (k < last && k > km) km = k;
      }
      for (int off = 32; off; off >>= 1){
        const unsigned long long o = shfl64_xor(km, off);
        km = (o > km) ? o : km;
      }
      if (lane == 0) sel[t10] = km;
      last = km;   // reduce result is wave-uniform
    }
  }
  __syncthreads();
  if (tid == 0){
    float top = 0.f;
    for (int t10 = 0; t10 < 10; ++t10)
      if (sel[t10]) top += __uint_as_float((unsigned)(sel[t10] >> 13));
    float strong = 0.f, dest0 = 0.f, dest1 = 0.f;
    if (sel[0]){
      const unsigned e0 = (unsigned)(sel[0] & 8191ULL);
      dest0 = dens[e0]; dest1 = dens[death[e0]];
    }
    for (int t10 = 1; t10 < 10; ++t10){
      if (!sel[t10]) continue;
      const unsigned e = (unsigned)(sel[t10] & 8191ULL);
      const float a = dens[e] - dest0;
      const float b = dens[death[e]] - dest1;
      strong += sqrtf(a*a + b*b);
    }
    out[0] = (S - top) / 1.41421356237309515f + strong;
  }
}

// =====================================================================
// launch — 7 dispatches (MF path) / 5 (fallback)
// =====================================================================
extern "C" void kernel_launch(void* const* d_in, const int* in_sizes, int n_in,
                              void* d_out, int out_size, void* d_ws, size_t ws_size,
                              hipStream_t stream){
  const float* x = (const float*)d_in[0];
  char* w = (char*)d_ws;
  float*          sq     = (float*)(w + 0);                 // 32KB
  float*          res    = (float*)(w + 32768);             // 32KB
  float*          dens_s = (float*)(w + 65536);             // 32KB
  unsigned short* rank   = (unsigned short*)(w + 98304);    // 16KB
  unsigned short* nn16   = (unsigned short*)(w + 114688);   // 256KB
  unsigned short* ups_t  = (unsigned short*)(w + 376832);   // 256KB (edge ping-pong in k_msf)
  float*          xT     = (float*)(w + 655360);            // 2MB (edges alias after k_samp)
  uint4*          xfrag  = (uint4*)(w + 2752512);           // 1MB
  float*          tub    = (float*)(w + 3801088);           // 32KB
  unsigned char*  nib    = (unsigned char*)(w + 3833856);   // 8MB
  const int use_xt  = (ws_size >= (size_t)2752512) ? 1 : 0;
  const int use_mf2 = (ws_size >= (size_t)(3833856 + 8*1024*1024)) ? 1 : 0;
  unsigned long long* edges = use_xt ? (unsigned long long*)(w + 655360)
                                     : (unsigned long long*)(w + 114688);
  const int edgecap = use_xt ? 262143 : 32767;

  k_pre<<<128, 256, 0, stream>>>(x, xT, sq, use_xt, xfrag, use_mf2);
  if (use_mf2){
    k_samp<true><<<1024, 256, 0, stream>>>(x, xT, sq, tub);
    k_filt<<<1024, 256, 0, stream>>>(x, sq, tub, xfrag, nib);
    k_csort<<<1024, 256, 0, stream>>>(x, sq, tub, nib, res, nn16);
  } else if (use_xt){
    k_cand<true ><<<1024, 256, 0, stream>>>(x, xT, sq, res, nn16);
  } else {
    k_cand<false><<<1024, 256, 0, stream>>>(x, xT, sq, res, nn16);
  }
  k_rank<<<64, 256, 0, stream>>>(res, rank, dens_s);
  k_ups <<<32, 256, 0, stream>>>(rank, nn16, ups_t);
  k_msf <<<1, 1024, 0, stream>>>(dens_s, ups_t, edges, edgecap, (float*)d_out);
}